// Round 2
// baseline (1099.613 us; speedup 1.0000x reference)
//
#include <hip/hip_runtime.h>

// GNN NNConv, N=25000, E=50000, C=49, 3 live layers (layer 3 is dead code).
// msg[e,o] = sum_k t[e,k]*U_k[src,o] + U_b[src,o];  U computed per NODE.
// All dense per-node GEMVs: node-per-thread, h-row in VGPRs, transposed W
// via uniform scalar loads (SGPR broadcast), LDS-staged coalesced row I/O.

#define N 25000
#define E 50000
#define C 49
#define C2 196
#define SLOPE 0.01f

__device__ __forceinline__ float leaky(float v) { return v > 0.f ? v : SLOPE * v; }

// Build transposed weights: wtu[l][c=kk*49+o][i], rwt[l][o][i], lwt[c][i]
__global__ void wt_kernel(const float* __restrict__ w2, const float* __restrict__ b2,
                          const float* __restrict__ rw, const float* __restrict__ lw,
                          float* __restrict__ wtu, float* __restrict__ rwt,
                          float* __restrict__ lwt) {
    int idx = blockIdx.x * 256 + threadIdx.x;
    if (idx < 3 * C2 * C) {
        int l = idx / (C2 * C), r = idx % (C2 * C), c = r / C, i = r % C;
        int kk = c / C ? 0 : 0;  // placeholder to keep compiler quiet
        kk = c / C;              // 0..3 via below
        kk = (r / C) / C;        // wrong path guard (unused)
        // c in [0,196): kk = c/49, o = c%49
        int k2 = c / C;
        int o = c % C;
        wtu[idx] = (k2 < 3) ? w2[(l * 3 + k2) * (C * C) + i * C + o]
                            : b2[l * (C * C) + i * C + o];
        return;
    }
    int j = idx - 3 * C2 * C;
    if (j < 3 * C * C) {
        int l = j / (C * C), r = j % (C * C), o = r / C, i = r % C;
        rwt[j] = rw[l * (C * C) + i * C + o];
        return;
    }
    int m = j - 3 * C * C;
    if (m < C * 56) {
        int c = m / 56, i = m % 56;
        lwt[m] = lw[i * C + c];
    }
}

__global__ void deg_kernel(const int* __restrict__ ei, float* __restrict__ deg) {
    int e = blockIdx.x * 256 + threadIdx.x;
    if (e < E) atomicAdd(&deg[ei[E + e]], 1.0f);
}

// h = leaky(x @ lin_w + lin_b); node-per-thread GEMV 56->49; writes h and out (JK init)
__global__ void h2_kernel(const float* __restrict__ x, const float* __restrict__ lwt,
                          const float* __restrict__ lb, float* __restrict__ h,
                          float* __restrict__ out) {
    __shared__ float lds[256 * 57];
    int t = threadIdx.x, base = blockIdx.x * 256;
    int nv = min(256, N - base);
    for (int e = t; e < nv * 56; e += 256) lds[(e / 56) * 57 + (e % 56)] = x[(size_t)base * 56 + e];
    __syncthreads();
    if (t < nv) {
        float xr[56];
#pragma unroll
        for (int i = 0; i < 56; i++) xr[i] = lds[t * 57 + i];
#pragma unroll 1
        for (int c = 0; c < C; c++) {
            float a = lb[c];
#pragma unroll
            for (int i = 0; i < 56; i++) a += xr[i] * lwt[c * 56 + i];
            lds[t * 57 + c] = leaky(a);
        }
    }
    __syncthreads();
    for (int e = t; e < nv * 49; e += 256) {
        float v = lds[(e / 49) * 57 + (e % 49)];
        h[(size_t)base * 49 + e] = v;
        out[(size_t)base * 49 + e] = v;
    }
}

// per-edge MLP hidden for all 3 layers
__global__ void t_kernel(const float* __restrict__ ea, const float* __restrict__ w1,
                         const float* __restrict__ b1, float* __restrict__ T) {
    int e = blockIdx.x * 256 + threadIdx.x;
    if (e >= E) return;
    float a[10];
#pragma unroll
    for (int j = 0; j < 10; j++) a[j] = ea[e * 10 + j];
#pragma unroll
    for (int l = 0; l < 3; l++) {
#pragma unroll
        for (int k = 0; k < 3; k++) {
            float acc = b1[l * 3 + k];
#pragma unroll
            for (int j = 0; j < 10; j++) acc += a[j] * w1[l * 30 + j * 3 + k];
            T[(l * E + e) * 3 + k] = fmaxf(acc, 0.f);
        }
    }
}

// MODE 0: U = h @ Wcat (in = h).  MODE 1: hv = leaky(in*sc+sh) [BN of prev layer],
// write hnext + accumulate JK out, then U = hv @ Wcat.
// st layout per layer: S[0..48], Q[64..112], scale[128..176], shift[192..240]
template <int MODE>
__global__ void uni_kernel(const float* __restrict__ in, const float* __restrict__ st,
                           const float* __restrict__ wtu, float* __restrict__ hnext,
                           float* __restrict__ out, float* __restrict__ U) {
    __shared__ float lds[256 * 49];
    int t = threadIdx.x, base = blockIdx.x * 256;
    int nv = min(256, N - base);
    int cnt = nv * 49;
    for (int e = t; e < cnt; e += 256) lds[e] = in[(size_t)base * 49 + e];
    __syncthreads();
    if (t < nv) {
        float hv[49];
        if (MODE == 1) {
#pragma unroll
            for (int i = 0; i < C; i++) {
                float v = lds[t * 49 + i] * st[128 + i] + st[192 + i];
                v = leaky(v);
                hv[i] = v;
                lds[t * 49 + i] = v;
            }
        } else {
#pragma unroll
            for (int i = 0; i < C; i++) hv[i] = lds[t * 49 + i];
        }
        float* urow = U + (size_t)(base + t) * C2;
#pragma unroll 1
        for (int c0 = 0; c0 < C2; c0 += 4) {
            float a0 = 0.f, a1 = 0.f, a2 = 0.f, a3 = 0.f;
#pragma unroll
            for (int i = 0; i < C; i++) {
                float h_ = hv[i];
                a0 += h_ * wtu[(c0 + 0) * C + i];
                a1 += h_ * wtu[(c0 + 1) * C + i];
                a2 += h_ * wtu[(c0 + 2) * C + i];
                a3 += h_ * wtu[(c0 + 3) * C + i];
            }
            float4 v4 = make_float4(a0, a1, a2, a3);
            *reinterpret_cast<float4*>(urow + c0) = v4;
        }
    }
    if (MODE == 1) {
        __syncthreads();
        for (int e = t; e < cnt; e += 256) {
            float v = lds[e];
            hnext[(size_t)base * 49 + e] = v;
            out[(size_t)base * 49 + e] += v;
        }
    }
}

// wave per edge: gather 4 U-chunks of src, combine with t, atomic-scatter to dst
__global__ void edge_kernel(const int* __restrict__ ei, const float* __restrict__ T,
                            const float* __restrict__ U, float* __restrict__ agg) {
    int wid = (blockIdx.x * 256 + threadIdx.x) >> 6;
    int lane = threadIdx.x & 63;
    if (wid >= E) return;
    int s = __builtin_amdgcn_readfirstlane(ei[wid]);
    int d = __builtin_amdgcn_readfirstlane(ei[E + wid]);
    float t0 = T[wid * 3], t1 = T[wid * 3 + 1], t2 = T[wid * 3 + 2];
    if (lane < C) {
        const float* u = U + (size_t)s * C2;
        float m = t0 * u[lane] + t1 * u[C + lane] + t2 * u[98 + lane] + u[147 + lane];
        atomicAdd(&agg[d * C + lane], m);
    }
}

// pre = agg/denom + h @ root_w + conv_b (in place on agg) + per-channel partial stats
__global__ void prestats_kernel(const float* __restrict__ h, const float* __restrict__ rwt,
                                const float* __restrict__ cb, const float* __restrict__ deg,
                                float* __restrict__ agg, float* __restrict__ st) {
    __shared__ float ah[128 * 49];
    __shared__ float hh[128 * 49];
    int t = threadIdx.x, base = blockIdx.x * 128;
    int nv = min(128, N - base);
    int cnt = nv * 49;
    for (int e = t; e < cnt; e += 128) {
        ah[e] = agg[(size_t)base * 49 + e];
        hh[e] = h[(size_t)base * 49 + e];
    }
    __syncthreads();
    if (t < nv) {
        float inv = 1.0f / fmaxf(deg[base + t], 1.0f);
        float hr[49];
#pragma unroll
        for (int i = 0; i < C; i++) hr[i] = hh[t * 49 + i];
        float prow[49];
#pragma unroll 2
        for (int c = 0; c < C; c++) {
            float a = cb[c] + ah[t * 49 + c] * inv;
#pragma unroll
            for (int i = 0; i < C; i++) a += hr[i] * rwt[c * 49 + i];
            prow[c] = a;
        }
#pragma unroll
        for (int c = 0; c < C; c++) ah[t * 49 + c] = prow[c];
    }
    __syncthreads();
    for (int e = t; e < cnt; e += 128) agg[(size_t)base * 49 + e] = ah[e];
    if (t < 98) {
        int g = t / C, c = t % C;
        float s = 0.f, q = 0.f;
        for (int r = g; r < nv; r += 2) {
            float v = ah[r * 49 + c];
            s += v;
            q += v * v;
        }
        atomicAdd(&st[c], s);
        atomicAdd(&st[64 + c], q);
    }
}

__global__ void bnfin_kernel(float* __restrict__ st, const float* __restrict__ gamma,
                             const float* __restrict__ beta) {
    int c = threadIdx.x;
    if (c < C) {
        float inv_n = 1.0f / (float)N;
        float mu = st[c] * inv_n;
        float var = st[64 + c] * inv_n - mu * mu;
        float sc = rsqrtf(var + 1e-5f) * gamma[c];
        st[128 + c] = sc;
        st[192 + c] = beta[c] - mu * sc;
    }
}

// last layer: out += leaky(pre*sc+sh)
__global__ void fnorm_kernel(const float* __restrict__ pre, const float* __restrict__ st,
                             float* __restrict__ out) {
    int idx = blockIdx.x * 256 + threadIdx.x;
    if (idx >= N * C) return;
    int c = idx % C;
    out[idx] += leaky(pre[idx] * st[128 + c] + st[192 + c]);
}

extern "C" void kernel_launch(void* const* d_in, const int* in_sizes, int n_in,
                              void* d_out, int out_size, void* d_ws, size_t ws_size,
                              hipStream_t stream) {
    const float* x  = (const float*)d_in[0];
    const int* ei   = (const int*)d_in[1];
    const float* ea = (const float*)d_in[2];
    const float* lw = (const float*)d_in[3];
    const float* lb = (const float*)d_in[4];
    const float* w1 = (const float*)d_in[5];
    const float* b1 = (const float*)d_in[6];
    const float* w2 = (const float*)d_in[7];
    const float* b2 = (const float*)d_in[8];
    const float* rw = (const float*)d_in[9];
    const float* cb = (const float*)d_in[10];
    const float* gm = (const float*)d_in[11];
    const float* bt = (const float*)d_in[12];
    float* out = (float*)d_out;

    float* ws  = (float*)d_ws;
    float* deg = ws;               // N
    float* agg = deg + N;          // N*C
    float* st  = agg + N * C;      // 3*256
    float* hA  = st + 768;         // N*C
    float* hB  = hA + N * C;       // N*C
    float* U   = hB + N * C;       // N*196
    float* T   = U + N * C2;       // 3*E*3
    float* wtu = T + 9 * E;        // 3*196*49
    float* rwt = wtu + 3 * C2 * C; // 3*2401
    float* lwt = rwt + 3 * C * C;  // 49*56

    // zero deg + agg(layer0) + all stats in one shot
    hipMemsetAsync(deg, 0, (size_t)(N + N * C + 768) * sizeof(float), stream);
    wt_kernel<<<(3 * C2 * C + 3 * C * C + C * 56 + 255) / 256, 256, 0, stream>>>(
        w2, b2, rw, lw, wtu, rwt, lwt);
    deg_kernel<<<(E + 255) / 256, 256, 0, stream>>>(ei, deg);
    h2_kernel<<<(N + 255) / 256, 256, 0, stream>>>(x, lwt, lb, hA, out);
    t_kernel<<<(E + 255) / 256, 256, 0, stream>>>(ea, w1, b1, T);

    float* cur = hA;
    float* nxt = hB;
    for (int l = 0; l < 3; l++) {
        if (l == 0) {
            uni_kernel<0><<<(N + 255) / 256, 256, 0, stream>>>(cur, st, wtu, nullptr, nullptr, U);
        } else {
            uni_kernel<1><<<(N + 255) / 256, 256, 0, stream>>>(
                agg, st + (l - 1) * 256, wtu + l * C2 * C, nxt, out, U);
            float* tmp = cur; cur = nxt; nxt = tmp;
            hipMemsetAsync(agg, 0, (size_t)N * C * sizeof(float), stream);
        }
        edge_kernel<<<E / 4, 256, 0, stream>>>(ei, T + (size_t)l * E * 3, U, agg);
        prestats_kernel<<<(N + 127) / 128, 128, 0, stream>>>(
            cur, rwt + l * C * C, cb + l * C, deg, agg, st + l * 256);
        bnfin_kernel<<<1, 64, 0, stream>>>(st + l * 256, gm + l * C, bt + l * C);
    }
    fnorm_kernel<<<(N * C + 255) / 256, 256, 0, stream>>>(agg, st + 2 * 256, out);
}

// Round 3
// 317.252 us; speedup vs baseline: 3.4661x; 3.4661x over previous
//
#include <hip/hip_runtime.h>

// GNN NNConv, N=25000, E=50000, C=49, 3 live layers (layer 3 of ref is dead code).
// msg[e,o] = sum_k t[e,k]*U_k[src,o] + U_b[src,o];  U computed per NODE (GEMM),
// edges only gather+combine+scatter.
//
// Dense kernels: lane = output channel (coalesced W loads, W column in VGPRs),
// loop over 64 nodes/block with h-row broadcast out of LDS (uniform address).

#define N 25000
#define E 50000
#define C 49
#define C2 196
#define SLOPE 0.01f

__device__ __forceinline__ float leaky(float v) { return v > 0.f ? v : SLOPE * v; }

__global__ void deg_kernel(const int* __restrict__ ei, float* __restrict__ deg) {
    int e = blockIdx.x * 256 + threadIdx.x;
    if (e < E) atomicAdd(&deg[ei[E + e]], 1.0f);
}

// h = leaky(x @ lin_w + lin_b). Block = 64 nodes. Thread (r=t/64, c=t&63), c<49
// active; group r handles nodes r, r+4, ... (16 each). lin_w[i*49+c]: c-contig.
__global__ __launch_bounds__(256) void h2_kernel(const float* __restrict__ x,
                                                 const float* __restrict__ lw,
                                                 const float* __restrict__ lb,
                                                 float* __restrict__ h,
                                                 float* __restrict__ out) {
    __shared__ float xs[64][56];
    int t = threadIdx.x, base = blockIdx.x * 64;
    int nv = min(64, N - base);
    for (int e = t; e < nv * 56; e += 256) xs[e / 56][e % 56] = x[(size_t)base * 56 + e];
    __syncthreads();
    int r = t >> 6, c = t & 63;
    if (c < C) {
        float w[56];
#pragma unroll
        for (int i = 0; i < 56; i++) w[i] = lw[i * C + c];
        float bias = lb[c];
        for (int n = r; n < nv; n += 4) {
            float acc = bias;
#pragma unroll
            for (int i4 = 0; i4 < 14; i4++) {
                float4 hv = *reinterpret_cast<const float4*>(&xs[n][i4 * 4]);
                acc += hv.x * w[i4 * 4] + hv.y * w[i4 * 4 + 1] + hv.z * w[i4 * 4 + 2] +
                       hv.w * w[i4 * 4 + 3];
            }
            acc = leaky(acc);
            h[(size_t)(base + n) * C + c] = acc;
            out[(size_t)(base + n) * C + c] = acc;
        }
    }
}

// per-edge MLP hidden for all 3 layers
__global__ void t_kernel(const float* __restrict__ ea, const float* __restrict__ w1,
                         const float* __restrict__ b1, float* __restrict__ T) {
    int e = blockIdx.x * 256 + threadIdx.x;
    if (e >= E) return;
    float a[10];
#pragma unroll
    for (int j = 0; j < 10; j++) a[j] = ea[e * 10 + j];
#pragma unroll
    for (int l = 0; l < 3; l++) {
#pragma unroll
        for (int k = 0; k < 3; k++) {
            float acc = b1[l * 3 + k];
#pragma unroll
            for (int j = 0; j < 10; j++) acc += a[j] * w1[l * 30 + j * 3 + k];
            T[(l * E + e) * 3 + k] = fmaxf(acc, 0.f);
        }
    }
}

// U[n][c] = sum_i hv[n][i] * W[i][c], c in [0,196): W col from w2 (k=c/49) or b2.
// MODE 1: hv = leaky(in*scale+shift) (BN of prev layer), also write hnext + JK out.
// Block = 64 nodes, 256 threads, lane c = output channel, W col in VGPRs.
template <int MODE>
__global__ __launch_bounds__(256) void uni_kernel(const float* __restrict__ in,
                                                  const float* __restrict__ st,
                                                  const float* __restrict__ w2,
                                                  const float* __restrict__ b2,
                                                  float* __restrict__ hnext,
                                                  float* __restrict__ out,
                                                  float* __restrict__ U) {
    __shared__ float hs[64][52];
    __shared__ float scl[52], sft[52];
    int t = threadIdx.x, base = blockIdx.x * 64;
    int nv = min(64, N - base);
    if (MODE == 1) {
        if (t < C) { scl[t] = st[128 + t]; sft[t] = st[192 + t]; }
        __syncthreads();
    }
    for (int e = t; e < nv * C; e += 256) {
        int n = e / C, i = e % C;
        float v = in[(size_t)base * C + e];
        if (MODE == 1) {
            v = leaky(v * scl[i] + sft[i]);
            hnext[(size_t)base * C + e] = v;
            out[(size_t)base * C + e] += v;
        }
        hs[n][i] = v;
    }
    for (int j = t; j < 64 * 3; j += 256) hs[j / 3][C + j % 3] = 0.f;
    __syncthreads();
    int c = t;
    if (c < C2) {
        int k = c / C, o = c % C;
        const float* Wp = (k < 3 ? w2 + k * (C * C) : b2) + o;
        float w[52];
#pragma unroll
        for (int i = 0; i < C; i++) w[i] = Wp[i * C];
        w[49] = w[50] = w[51] = 0.f;
        for (int n = 0; n < nv; n++) {
            float acc = 0.f;
#pragma unroll
            for (int i4 = 0; i4 < 13; i4++) {
                float4 hv = *reinterpret_cast<const float4*>(&hs[n][i4 * 4]);
                acc += hv.x * w[i4 * 4] + hv.y * w[i4 * 4 + 1] + hv.z * w[i4 * 4 + 2] +
                       hv.w * w[i4 * 4 + 3];
            }
            U[(size_t)(base + n) * C2 + c] = acc;
        }
    }
}

// wave per edge: gather 4 U-chunks of src, combine with t, atomic-scatter to dst
__global__ void edge_kernel(const int* __restrict__ ei, const float* __restrict__ T,
                            const float* __restrict__ U, float* __restrict__ agg) {
    int wid = (blockIdx.x * 256 + threadIdx.x) >> 6;
    int lane = threadIdx.x & 63;
    if (wid >= E) return;
    int s = __builtin_amdgcn_readfirstlane(ei[wid]);
    int d = __builtin_amdgcn_readfirstlane(ei[E + wid]);
    float t0 = T[wid * 3], t1 = T[wid * 3 + 1], t2 = T[wid * 3 + 2];
    if (lane < C) {
        const float* u = U + (size_t)s * C2;
        float m = t0 * u[lane] + t1 * u[C + lane] + t2 * u[98 + lane] + u[147 + lane];
        atomicAdd(&agg[d * C + lane], m);
    }
}

// pre = agg/denom + h @ root_w + conv_b (in place on agg) + per-channel stats.
// Block = 64 nodes; thread (r=t>>6, c=t&63), c<49 active; rw[i*49+c]: c-contig.
__global__ __launch_bounds__(256) void prestats_kernel(const float* __restrict__ h,
                                                        const float* __restrict__ rw,
                                                        const float* __restrict__ cb,
                                                        const float* __restrict__ deg,
                                                        float* __restrict__ agg,
                                                        float* __restrict__ st) {
    __shared__ float hs[64][52];
    __shared__ float sred[8][64];
    int t = threadIdx.x, base = blockIdx.x * 64;
    int nv = min(64, N - base);
    for (int e = t; e < nv * C; e += 256) hs[e / C][e % C] = h[(size_t)base * C + e];
    for (int j = t; j < 64 * 3; j += 256) hs[j / 3][C + j % 3] = 0.f;
    __syncthreads();
    int r = t >> 6, c = t & 63;
    float s = 0.f, q = 0.f;
    if (c < C) {
        float w[52];
#pragma unroll
        for (int i = 0; i < C; i++) w[i] = rw[i * C + c];
        w[49] = w[50] = w[51] = 0.f;
        float bias = cb[c];
        for (int n = r; n < nv; n += 4) {
            float inv = 1.0f / fmaxf(deg[base + n], 1.0f);
            float acc = bias + agg[(size_t)(base + n) * C + c] * inv;
#pragma unroll
            for (int i4 = 0; i4 < 13; i4++) {
                float4 hv = *reinterpret_cast<const float4*>(&hs[n][i4 * 4]);
                acc += hv.x * w[i4 * 4] + hv.y * w[i4 * 4 + 1] + hv.z * w[i4 * 4 + 2] +
                       hv.w * w[i4 * 4 + 3];
            }
            agg[(size_t)(base + n) * C + c] = acc;
            s += acc;
            q += acc * acc;
        }
    }
    if (c < C) { sred[r][c] = s; sred[4 + r][c] = q; }
    __syncthreads();
    if (t < C) {
        float S = sred[0][t] + sred[1][t] + sred[2][t] + sred[3][t];
        float Q = sred[4][t] + sred[5][t] + sred[6][t] + sred[7][t];
        atomicAdd(&st[t], S);
        atomicAdd(&st[64 + t], Q);
    }
}

__global__ void bnfin_kernel(float* __restrict__ st, const float* __restrict__ gamma,
                             const float* __restrict__ beta) {
    int c = threadIdx.x;
    if (c < C) {
        float inv_n = 1.0f / (float)N;
        float mu = st[c] * inv_n;
        float var = st[64 + c] * inv_n - mu * mu;
        float sc = rsqrtf(var + 1e-5f) * gamma[c];
        st[128 + c] = sc;
        st[192 + c] = beta[c] - mu * sc;
    }
}

// last layer: out += leaky(pre*sc+sh)
__global__ void fnorm_kernel(const float* __restrict__ pre, const float* __restrict__ st,
                             float* __restrict__ out) {
    int idx = blockIdx.x * 256 + threadIdx.x;
    if (idx >= N * C) return;
    int c = idx % C;
    out[idx] += leaky(pre[idx] * st[128 + c] + st[192 + c]);
}

extern "C" void kernel_launch(void* const* d_in, const int* in_sizes, int n_in,
                              void* d_out, int out_size, void* d_ws, size_t ws_size,
                              hipStream_t stream) {
    const float* x  = (const float*)d_in[0];
    const int* ei   = (const int*)d_in[1];
    const float* ea = (const float*)d_in[2];
    const float* lw = (const float*)d_in[3];
    const float* lb = (const float*)d_in[4];
    const float* w1 = (const float*)d_in[5];
    const float* b1 = (const float*)d_in[6];
    const float* w2 = (const float*)d_in[7];
    const float* b2 = (const float*)d_in[8];
    const float* rw = (const float*)d_in[9];
    const float* cb = (const float*)d_in[10];
    const float* gm = (const float*)d_in[11];
    const float* bt = (const float*)d_in[12];
    float* out = (float*)d_out;

    float* ws  = (float*)d_ws;
    float* deg = ws;               // N
    float* agg = deg + N;          // N*C
    float* st  = agg + N * C;      // 3*256
    float* hA  = st + 768;         // N*C
    float* hB  = hA + N * C;       // N*C
    float* U   = hB + N * C;       // N*196
    float* T   = U + (size_t)N * C2; // 3*E*3

    // zero deg + agg(layer0) + all stats in one shot
    hipMemsetAsync(deg, 0, (size_t)(N + N * C + 768) * sizeof(float), stream);
    deg_kernel<<<(E + 255) / 256, 256, 0, stream>>>(ei, deg);
    h2_kernel<<<(N + 63) / 64, 256, 0, stream>>>(x, lw, lb, hA, out);
    t_kernel<<<(E + 255) / 256, 256, 0, stream>>>(ea, w1, b1, T);

    float* cur = hA;
    float* nxt = hB;
    for (int l = 0; l < 3; l++) {
        if (l == 0) {
            uni_kernel<0><<<(N + 63) / 64, 256, 0, stream>>>(
                cur, st, w2, b2, nullptr, nullptr, U);
        } else {
            uni_kernel<1><<<(N + 63) / 64, 256, 0, stream>>>(
                agg, st + (l - 1) * 256, w2 + l * 3 * (C * C), b2 + l * (C * C), nxt, out, U);
            float* tmp = cur; cur = nxt; nxt = tmp;
            hipMemsetAsync(agg, 0, (size_t)N * C * sizeof(float), stream);
        }
        edge_kernel<<<E / 4, 256, 0, stream>>>(ei, T + (size_t)l * E * 3, U, agg);
        prestats_kernel<<<(N + 63) / 64, 256, 0, stream>>>(
            cur, rw + l * (C * C), cb + l * C, deg, agg, st + l * 256);
        bnfin_kernel<<<1, 64, 0, stream>>>(st + l * 256, gm + l * C, bt + l * C);
    }
    fnorm_kernel<<<(N * C + 255) / 256, 256, 0, stream>>>(agg, st + 2 * 256, out);
}